// Round 12
// baseline (399.265 us; speedup 1.0000x reference)
//
#include <hip/hip_runtime.h>
#include <stdint.h>

typedef float  f32x4 __attribute__((ext_vector_type(4)));
typedef short  s16x8 __attribute__((ext_vector_type(8)));
typedef unsigned short u16;

#define KK 32768   /* NN*DD */

__device__ __forceinline__ u16 f2bf_rn(float f) {
  uint32_t u = __float_as_uint(f);
  u += 0x7fffu + ((u >> 16) & 1u);
  return (u16)(u >> 16);
}
__device__ __forceinline__ float bf2f(u16 h) {
  return __uint_as_float(((uint32_t)h) << 16);
}

// ---------------------------------------------------------------------------
// Kernel A: g_t[b][c][k] = x[b,s,c] * W[d,c], k = s*32+d, LINEAR layout,
// bf16 hi/lo planes.
// ---------------------------------------------------------------------------
__global__ void build_g(const float* __restrict__ x, const float* __restrict__ W,
                        u16* __restrict__ ghi, u16* __restrict__ glo) {
  int t  = blockIdx.x * 256 + threadIdx.x;
  int k0 = (t & 4095) << 3;
  int c  = (t >> 12) & 63;
  int b  = t >> 18;
  int s  = k0 >> 5;
  int d0 = k0 & 31;
  float xv = x[(((b << 10) + s) << 6) + c];
  s16x8 vh, vl;
#pragma unroll
  for (int i = 0; i < 8; ++i) {
    float g = xv * W[((d0 + i) << 6) + c];
    u16 h = f2bf_rn(g);
    vh[i] = (short)h;
    vl[i] = (short)f2bf_rn(g - bf2f(h));
  }
  size_t off = (((size_t)((b << 6) + c)) << 15) + (size_t)k0;
  *reinterpret_cast<s16x8*>(ghi + off) = vh;
  *reinterpret_cast<s16x8*>(glo + off) = vl;
}

// ---------------------------------------------------------------------------
// DIAGNOSTIC: pure-read HBM stream over 805 MiB of untouched ws (0xAA).
// 2048 blocks x 256 thr = 32 waves/CU; coalesced dwordx4 grid-stride,
// 4 independent accumulators. Measures the pure-READ ceiling.
// ---------------------------------------------------------------------------
__global__ __launch_bounds__(256) void readbench(const float* __restrict__ src,
                                                 float* __restrict__ sink) {
  const size_t gid    = (size_t)blockIdx.x * 256 + threadIdx.x;
  const size_t stride = (size_t)2048 * 256;          // threads
  const f32x4* p = reinterpret_cast<const f32x4*>(src);
  f32x4 s0 = {0,0,0,0}, s1 = s0, s2 = s0, s3 = s0;
#pragma unroll 6
  for (int j = 0; j < 96; j += 4) {
    s0 += p[gid + (size_t)(j + 0) * stride];
    s1 += p[gid + (size_t)(j + 1) * stride];
    s2 += p[gid + (size_t)(j + 2) * stride];
    s3 += p[gid + (size_t)(j + 3) * stride];
  }
  f32x4 s = s0 + s1 + s2 + s3;
  sink[gid] = s[0] + s[1] + s[2] + s[3];
}

// ---------------------------------------------------------------------------
// Kernel B: round-10 streaming GEMM with `reps` internal repetitions
// (idempotent: recomputes the identical `part`) so one ~230us dispatch
// surfaces in rocprof top-5 with its own counters.
// ---------------------------------------------------------------------------
#define MFMA16(A_, B_, C_) __builtin_amdgcn_mfma_f32_16x16x32_bf16((A_), (B_), (C_), 0, 0, 0)

__global__ __launch_bounds__(512) void gemm_stream(
    const float* __restrict__ kb, const u16* __restrict__ ghi,
    const u16* __restrict__ glo, float* __restrict__ part, int reps) {
  __shared__ unsigned char lds[98304];

  const int tid = threadIdx.x;
  const int w   = tid >> 6;
  const int l   = tid & 63;
  const int lr  = l & 15;
  const int lk  = l >> 4;
  const int ks  = blockIdx.y;
  const int b   = blockIdx.z;
  const int rf  = w >> 2;        // row-frag 0..1 (16 rows each)
  const int cf  = w & 3;         // col-frag 0..3

  // ---- B fragments -> registers, once ----
  s16x8 BH[8], BL[8];
  {
    const size_t bo = (((size_t)((b << 6) + (cf << 4) + lr)) << 15)
                    + (size_t)(ks << 8) + (size_t)(lk << 3);
    const u16* ph = ghi + bo;
    const u16* pq = glo + bo;
#pragma unroll
    for (int kf = 0; kf < 8; ++kf) {
      BH[kf] = *reinterpret_cast<const s16x8*>(ph + kf * 32);
      BL[kf] = *reinterpret_cast<const s16x8*>(pq + kf * 32);
    }
  }

  // ---- A addressing ----
  const int rl   = tid >> 4;
  const int kc16 = (tid & 15) << 4;
  const float* apg = kb + (((size_t)((b << 10) + rl)) << 15)
                        + (size_t)(ks << 8) + (size_t)kc16;
  const int wb   = rl * 512;
  const int wswz = (rl & 7) << 4;
  const int arow = (rf << 4) + lr;
  const int arb  = arow * 512;
  const int aswz = (arow & 7) << 4;

  float* const pbase = part + (((size_t)((b << 7) + ks)) << 16);

  f32x4 ra[4], rb[4];

#define LOADA(R_, mt_) do {                                                  \
    const float* p_ = apg + ((size_t)(mt_) << 20);                           \
    R_[0] = *reinterpret_cast<const f32x4*>(p_);                             \
    R_[1] = *reinterpret_cast<const f32x4*>(p_ + 4);                         \
    R_[2] = *reinterpret_cast<const f32x4*>(p_ + 8);                         \
    R_[3] = *reinterpret_cast<const f32x4*>(p_ + 12);                        \
  } while (0)

#define CONV(R_, buf_) do {                                                  \
    unsigned char* base_ = lds + (buf_) * 32768;                             \
    s16x8 h_[2], o_[2];                                                      \
    _Pragma("unroll")                                                        \
    for (int j = 0; j < 16; ++j) {                                           \
      float f_ = R_[j >> 2][j & 3];                                          \
      uint32_t u_ = __float_as_uint(f_);                                     \
      ((short*)h_)[j] = (short)(u16)(u_ >> 16);                              \
      ((short*)o_)[j] = (short)f2bf_rn(f_ - __uint_as_float(u_ & 0xffff0000u)); \
    }                                                                        \
    *reinterpret_cast<s16x8*>(base_ + wb + (((kc16 << 1)     ) ^ wswz)) = h_[0]; \
    *reinterpret_cast<s16x8*>(base_ + wb + (((kc16 << 1) + 16) ^ wswz)) = h_[1]; \
    *reinterpret_cast<s16x8*>(base_ + 16384 + wb + (((kc16 << 1)     ) ^ wswz)) = o_[0]; \
    *reinterpret_cast<s16x8*>(base_ + 16384 + wb + (((kc16 << 1) + 16) ^ wswz)) = o_[1]; \
  } while (0)

#define MFMAPH(mt_) do {                                                     \
    const unsigned char* base_ = lds + ((mt_) % 3) * 32768;                  \
    f32x4 acc_ = {0.f, 0.f, 0.f, 0.f};                                       \
    _Pragma("unroll")                                                        \
    for (int kf = 0; kf < 8; ++kf) {                                         \
      int kb_ = (kf << 6) + (lk << 4);                                       \
      s16x8 ah_ = *reinterpret_cast<const s16x8*>(base_ + arb + (kb_ ^ aswz)); \
      s16x8 al_ = *reinterpret_cast<const s16x8*>(base_ + 16384 + arb + (kb_ ^ aswz)); \
      acc_ = MFMA16(ah_, BH[kf], acc_);                                      \
      acc_ = MFMA16(al_, BH[kf], acc_);                                      \
      acc_ = MFMA16(ah_, BL[kf], acc_);                                      \
    }                                                                        \
    _Pragma("unroll")                                                        \
    for (int i = 0; i < 4; ++i) {                                            \
      int rr_ = ((mt_) << 5) + (rf << 4) + (lk << 2) + i;                    \
      pbase[((size_t)rr_ << 6) + (cf << 4) + lr] = acc_[i];                  \
    }                                                                        \
  } while (0)

  for (int rep = 0; rep < reps; ++rep) {
    if (rep) {
      asm volatile("s_waitcnt vmcnt(0) lgkmcnt(0)" ::: "memory");
      __builtin_amdgcn_sched_barrier(0);
      __builtin_amdgcn_s_barrier();
    }
    // ---- prologue ----
    LOADA(ra, 0);
    LOADA(rb, 1);
    asm volatile("s_waitcnt vmcnt(4)" ::: "memory");
    __builtin_amdgcn_sched_barrier(0);
    CONV(ra, 0);
    LOADA(ra, 2);
    asm volatile("s_waitcnt vmcnt(4)" ::: "memory");
    __builtin_amdgcn_sched_barrier(0);
    CONV(rb, 1);
    LOADA(rb, 3);
    asm volatile("s_waitcnt lgkmcnt(0)" ::: "memory");
    __builtin_amdgcn_sched_barrier(0);
    __builtin_amdgcn_s_barrier();

    // ---- main loop ----
    for (int mt = 0; mt < 32; mt += 2) {
      MFMAPH(mt);
      asm volatile("s_waitcnt vmcnt(8)" ::: "memory");
      __builtin_amdgcn_sched_barrier(0);
      if (mt + 2 < 32) CONV(ra, (mt + 2) % 3);
      if (mt + 4 < 32) LOADA(ra, mt + 4);
      asm volatile("s_waitcnt lgkmcnt(0)" ::: "memory");
      __builtin_amdgcn_sched_barrier(0);
      __builtin_amdgcn_s_barrier();
      MFMAPH(mt + 1);
      asm volatile("s_waitcnt vmcnt(8)" ::: "memory");
      __builtin_amdgcn_sched_barrier(0);
      if (mt + 3 < 32) CONV(rb, (mt + 3) % 3);
      if (mt + 5 < 32) LOADA(rb, mt + 5);
      asm volatile("s_waitcnt lgkmcnt(0)" ::: "memory");
      __builtin_amdgcn_sched_barrier(0);
      __builtin_amdgcn_s_barrier();
    }
  }
#undef LOADA
#undef CONV
#undef MFMAPH
}

// ---------------------------------------------------------------------------
// Kernel C: per (b,r): reduce Sk partials + conv_bias -> LayerNorm -> MLP.
// ---------------------------------------------------------------------------
__device__ __forceinline__ float gelu_tanh(float v) {
  float u = 0.7978845608028654f * (v + 0.044715f * v * v * v);
  float e = __expf(2.0f * u);
  float th = 1.0f - 2.0f / (e + 1.0f);
  return 0.5f * v * (1.0f + th);
}

__global__ __launch_bounds__(256) void epilogue(
    const float* __restrict__ part, const float* __restrict__ conv_bias,
    const float* __restrict__ ln_scale, const float* __restrict__ ln_bias,
    const float* __restrict__ W1, const float* __restrict__ b1,
    const float* __restrict__ W2, const float* __restrict__ b2,
    float* __restrict__ out, int Sk) {
  __shared__ float red[4][64];
  __shared__ float nbuf[64];
  __shared__ float hbuf[256];

  const int tid = threadIdx.x;
  const int b = blockIdx.x >> 10;
  const int r = blockIdx.x & 1023;
  const int c = tid & 63;
  const int q = tid >> 6;

  float s = 0.0f;
  for (int ks = q; ks < Sk; ks += 4)
    s += part[(((size_t)(b * Sk + ks)) << 16) + ((size_t)r << 6) + c];
  red[q][c] = s;
  __syncthreads();

  if (q == 0) {
    float a = red[0][c] + red[1][c] + red[2][c] + red[3][c] + conv_bias[c];
    float sum = a;
#pragma unroll
    for (int off = 32; off >= 1; off >>= 1) sum += __shfl_xor(sum, off);
    float mu = sum * (1.0f / 64.0f);
    float d = a - mu;
    float ss = d * d;
#pragma unroll
    for (int off = 32; off >= 1; off >>= 1) ss += __shfl_xor(ss, off);
    float var = ss * (1.0f / 64.0f);
    nbuf[c] = d * rsqrtf(var + 1e-6f) * ln_scale[c] + ln_bias[c];
  }
  __syncthreads();

  {
    float acc = b1[tid];
#pragma unroll 8
    for (int cc = 0; cc < 64; ++cc) acc += nbuf[cc] * W1[(cc << 8) + tid];
    hbuf[tid] = gelu_tanh(acc);
  }
  __syncthreads();

  {
    float po = 0.0f;
#pragma unroll 8
    for (int jj = 0; jj < 64; ++jj) {
      int j = (q << 6) + jj;
      po += hbuf[j] * W2[(j << 6) + c];
    }
    red[q][c] = po;
  }
  __syncthreads();
  if (tid < 64) {
    float o = red[0][c] + red[1][c] + red[2][c] + red[3][c] + b2[c];
    out[(((size_t)(b << 10) + r) << 6) + c] = o;
  }
}

// ---------------------------------------------------------------------------
extern "C" void kernel_launch(void* const* d_in, const int* in_sizes, int n_in,
                              void* d_out, int out_size, void* d_ws, size_t ws_size,
                              hipStream_t stream) {
  const float* x         = (const float*)d_in[0];
  const float* kb        = (const float*)d_in[1];
  const float* kernel_W  = (const float*)d_in[2];
  const float* conv_bias = (const float*)d_in[3];
  const float* ln_scale  = (const float*)d_in[4];
  const float* ln_bias   = (const float*)d_in[5];
  const float* W1        = (const float*)d_in[6];
  const float* b1        = (const float*)d_in[7];
  const float* W2        = (const float*)d_in[8];
  const float* b2        = (const float*)d_in[9];
  float* out = (float*)d_out;

  // Workspace: ghi 8.4MB | glo 8.4MB | part 67MB | sink @112MiB (2MiB)
  //            | readbench region [128MiB, 128MiB+805MiB) -- never written.
  char* wsb = (char*)d_ws;
  u16* ghi = (u16*)wsb;
  u16* glo = (u16*)(wsb + 8388608);
  float* part = (float*)(wsb + 16777216);
  float* sink = (float*)(wsb + 117440512);            // 112 MiB
  const float* rsrc = (const float*)(wsb + 134217728); // 128 MiB
  const int Sk = 128;

  build_g<<<2048, 256, 0, stream>>>(x, kernel_W, ghi, glo);
  gemm_stream<<<dim3(1, Sk, 2), 512, 0, stream>>>(kb, ghi, glo, part, 3);
  readbench<<<2048, 256, 0, stream>>>(rsrc, sink);
  epilogue<<<dim3(2048), 256, 0, stream>>>(part, conv_bias, ln_scale, ln_bias,
                                           W1, b1, W2, b2, out, Sk);
}

// Round 14
// 188.586 us; speedup vs baseline: 2.1171x; 2.1171x over previous
//
#include <hip/hip_runtime.h>
#include <stdint.h>

typedef float  f32x4 __attribute__((ext_vector_type(4)));
typedef short  s16x8 __attribute__((ext_vector_type(8)));
typedef unsigned short u16;

#define KK 32768   /* NN*DD */

__device__ __forceinline__ u16 f2bf_rn(float f) {
  uint32_t u = __float_as_uint(f);
  u += 0x7fffu + ((u >> 16) & 1u);
  return (u16)(u >> 16);
}
__device__ __forceinline__ float bf2f(u16 h) {
  return __uint_as_float(((uint32_t)h) << 16);
}

// ---------------------------------------------------------------------------
// Kernel A: g_t[b][c][k] = x[b,s,c] * W[d,c], k = s*32+d, LINEAR layout,
// bf16 hi/lo planes. (GEMM holds B fragments in registers.)
// ---------------------------------------------------------------------------
__global__ void build_g(const float* __restrict__ x, const float* __restrict__ W,
                        u16* __restrict__ ghi, u16* __restrict__ glo) {
  int t  = blockIdx.x * 256 + threadIdx.x;
  int k0 = (t & 4095) << 3;
  int c  = (t >> 12) & 63;
  int b  = t >> 18;
  int s  = k0 >> 5;
  int d0 = k0 & 31;
  float xv = x[(((b << 10) + s) << 6) + c];
  s16x8 vh, vl;
#pragma unroll
  for (int i = 0; i < 8; ++i) {
    float g = xv * W[((d0 + i) << 6) + c];
    u16 h = f2bf_rn(g);
    vh[i] = (short)h;
    vl[i] = (short)f2bf_rn(g - bf2f(h));
  }
  size_t off = (((size_t)((b << 6) + c)) << 15) + (size_t)k0;
  *reinterpret_cast<s16x8*>(ghi + off) = vh;
  *reinterpret_cast<s16x8*>(glo + off) = vl;
}

// ---------------------------------------------------------------------------
// Kernel B: LDS-FREE streaming GEMM (round-12 diagnosis: prior kernels were
// LDS-throughput-bound, not memory-bound).
// Grid (2,128,2) x 256 thr. Global wave gw = blockIdx.x*4 + wave (0..7) per
// (ks,b); wave owns 16 rows x all 64 cols x k-window [ks*256,+256).
// B: 8kf x 4ct x {hi,lo} s16x8 in 128 VGPRs, loaded once from L3-resident g.
// A: loaded DIRECTLY in MFMA fragment layout (lane lr=row, lk*32B k-chunk,
// 2x dwordx4), depth-4 kf prefetch, exact in-order vmcnt counts.
// No LDS. No barriers. Double-buffered acc (store-WAR never drains pipeline).
// 8 rowgroups/wave, fully unrolled (static reg indexing).
// ---------------------------------------------------------------------------
#define MFMA16(A_, B_, C_) __builtin_amdgcn_mfma_f32_16x16x32_bf16((A_), (B_), (C_), 0, 0, 0)

__global__ __launch_bounds__(256, 2) void gemm_nolds(
    const float* __restrict__ kb, const u16* __restrict__ ghi,
    const u16* __restrict__ glo, float* __restrict__ part) {
  const int tid = threadIdx.x;
  const int gw  = blockIdx.x * 4 + (tid >> 6);   // 0..7
  const int l   = tid & 63;
  const int lr  = l & 15;                        // A row / B col within frag
  const int lk  = l >> 4;                        // k-group 0..3
  const int ks  = blockIdx.y;                    // k-window
  const int b   = blockIdx.z;

  // ---- B fragments -> 128 VGPRs, once ----
  s16x8 BH[8][4], BL[8][4];
#pragma unroll
  for (int kf = 0; kf < 8; ++kf)
#pragma unroll
    for (int ct = 0; ct < 4; ++ct) {
      size_t off = (((size_t)((b << 6) + (ct << 4) + lr)) << 15)
                 + (size_t)((ks << 8) + (kf << 5) + (lk << 3));
      BH[kf][ct] = *reinterpret_cast<const s16x8*>(ghi + off);
      BL[kf][ct] = *reinterpret_cast<const s16x8*>(glo + off);
    }

  const float* abase = kb + (((size_t)((b << 10) + (gw << 4) + lr)) << 15)
                          + (size_t)((ks << 8) + (lk << 3));
  float* const pbase = part + (((size_t)((b << 7) + ks)) << 16);

  f32x4 rawA[4][2];       // depth-4 circular raw-fragment buffer
  f32x4 accA[4], accB[4]; // double-buffered accumulators (per-rowgroup parity)

#define LDA(J_, KF_) do {                                                     \
    const float* p_ = abase + ((size_t)(J_) << 22) + (size_t)((KF_) << 5);    \
    rawA[(KF_) & 3][0] = *reinterpret_cast<const f32x4*>(p_);                 \
    rawA[(KF_) & 3][1] = *reinterpret_cast<const f32x4*>(p_ + 4);             \
  } while (0)

#define WAITV(N_) do {                                                        \
    asm volatile("s_waitcnt vmcnt(" #N_ ")" ::: "memory");                    \
    __builtin_amdgcn_sched_barrier(0);                                        \
  } while (0)

#define STEP(J_, KF_, ACC_, VN_) do {                                         \
    WAITV(VN_);                                                               \
    s16x8 ah_, al_;                                                           \
    _Pragma("unroll")                                                         \
    for (int e = 0; e < 8; ++e) {                                             \
      float f_ = rawA[(KF_) & 3][e >> 2][e & 3];                              \
      uint32_t u_ = __float_as_uint(f_);                                      \
      ((short*)&ah_)[e] = (short)(u16)(u_ >> 16);                             \
      ((short*)&al_)[e] = (short)f2bf_rn(f_ - __uint_as_float(u_ & 0xffff0000u)); \
    }                                                                         \
    if ((KF_) < 4) { LDA(J_, (KF_) + 4); }                                    \
    else if ((J_) + 1 < 8) { LDA((J_) + 1, (KF_) - 4); }                      \
    _Pragma("unroll")                                                         \
    for (int ct = 0; ct < 4; ++ct) {                                          \
      ACC_[ct] = MFMA16(ah_, BH[KF_][ct], ACC_[ct]);                          \
      ACC_[ct] = MFMA16(al_, BH[KF_][ct], ACC_[ct]);                          \
      ACC_[ct] = MFMA16(ah_, BL[KF_][ct], ACC_[ct]);                          \
    }                                                                         \
  } while (0)

#define ZERO(ACC_) do {                                                       \
    _Pragma("unroll")                                                         \
    for (int ct = 0; ct < 4; ++ct) ACC_[ct] = (f32x4){0.f, 0.f, 0.f, 0.f};    \
  } while (0)

#define STOREC(J_, ACC_) do {                                                 \
    float* pp_ = pbase + (((size_t)(((gw + 8 * (J_)) << 4) + (lk << 2))) << 6) + lr; \
    _Pragma("unroll")                                                         \
    for (int ct = 0; ct < 4; ++ct)                                            \
      _Pragma("unroll")                                                       \
      for (int i = 0; i < 4; ++i)                                             \
        pp_[((size_t)i << 6) + (ct << 4)] = ACC_[ct][i];                      \
  } while (0)

#define ROWGROUP(J_, ACC_, VA_, VB_) do {                                     \
    ZERO(ACC_);                                                               \
    STEP(J_, 0, ACC_, VA_); STEP(J_, 1, ACC_, VA_);                           \
    STEP(J_, 2, ACC_, VA_); STEP(J_, 3, ACC_, VA_);                           \
    STEP(J_, 4, ACC_, VB_); STEP(J_, 5, ACC_, VB_);                           \
    STEP(J_, 6, ACC_, VB_); STEP(J_, 7, ACC_, VB_);                           \
    STOREC(J_, ACC_);                                                         \
  } while (0)

  // prologue: first rowgroup's first 4 k-fragments in flight
  LDA(0, 0); LDA(0, 1); LDA(0, 2); LDA(0, 3);

  // vmcnt accounting (in-order): rowgroup 0 has no stores in flight -> 6.
  // rowgroups 1..7: kf0..3 see 16 pending stores + 6 younger loads -> 22;
  // kf4..7 see only the 6 younger loads -> 6 (stores are older, long done).
  ROWGROUP(0, accA,  6, 6);
  ROWGROUP(1, accB, 22, 6);
  ROWGROUP(2, accA, 22, 6);
  ROWGROUP(3, accB, 22, 6);
  ROWGROUP(4, accA, 22, 6);
  ROWGROUP(5, accB, 22, 6);
  ROWGROUP(6, accA, 22, 6);
  // last rowgroup: no further prefetch -> counts shrink on the tail
  ZERO(accB);
  STEP(7, 0, accB, 22); STEP(7, 1, accB, 22);
  STEP(7, 2, accB, 22); STEP(7, 3, accB, 22);
  STEP(7, 4, accB, 6);  STEP(7, 5, accB, 4);
  STEP(7, 6, accB, 2);  STEP(7, 7, accB, 0);
  STOREC(7, accB);

#undef LDA
#undef WAITV
#undef STEP
#undef ZERO
#undef STOREC
#undef ROWGROUP
}

// ---------------------------------------------------------------------------
// Kernel C: per (b,r): reduce Sk partials + conv_bias -> LayerNorm -> MLP.
// ---------------------------------------------------------------------------
__device__ __forceinline__ float gelu_tanh(float v) {
  float u = 0.7978845608028654f * (v + 0.044715f * v * v * v);
  float e = __expf(2.0f * u);
  float th = 1.0f - 2.0f / (e + 1.0f);
  return 0.5f * v * (1.0f + th);
}

__global__ __launch_bounds__(256) void epilogue(
    const float* __restrict__ part, const float* __restrict__ conv_bias,
    const float* __restrict__ ln_scale, const float* __restrict__ ln_bias,
    const float* __restrict__ W1, const float* __restrict__ b1,
    const float* __restrict__ W2, const float* __restrict__ b2,
    float* __restrict__ out, int Sk) {
  __shared__ float red[4][64];
  __shared__ float nbuf[64];
  __shared__ float hbuf[256];

  const int tid = threadIdx.x;
  const int b = blockIdx.x >> 10;
  const int r = blockIdx.x & 1023;
  const int c = tid & 63;
  const int q = tid >> 6;

  float s = 0.0f;
  for (int ks = q; ks < Sk; ks += 4)
    s += part[(((size_t)(b * Sk + ks)) << 16) + ((size_t)r << 6) + c];
  red[q][c] = s;
  __syncthreads();

  if (q == 0) {
    float a = red[0][c] + red[1][c] + red[2][c] + red[3][c] + conv_bias[c];
    float sum = a;
#pragma unroll
    for (int off = 32; off >= 1; off >>= 1) sum += __shfl_xor(sum, off);
    float mu = sum * (1.0f / 64.0f);
    float d = a - mu;
    float ss = d * d;
#pragma unroll
    for (int off = 32; off >= 1; off >>= 1) ss += __shfl_xor(ss, off);
    float var = ss * (1.0f / 64.0f);
    nbuf[c] = d * rsqrtf(var + 1e-6f) * ln_scale[c] + ln_bias[c];
  }
  __syncthreads();

  {
    float acc = b1[tid];
#pragma unroll 8
    for (int cc = 0; cc < 64; ++cc) acc += nbuf[cc] * W1[(cc << 8) + tid];
    hbuf[tid] = gelu_tanh(acc);
  }
  __syncthreads();

  {
    float po = 0.0f;
#pragma unroll 8
    for (int jj = 0; jj < 64; ++jj) {
      int j = (q << 6) + jj;
      po += hbuf[j] * W2[(j << 6) + c];
    }
    red[q][c] = po;
  }
  __syncthreads();
  if (tid < 64) {
    float o = red[0][c] + red[1][c] + red[2][c] + red[3][c] + b2[c];
    out[(((size_t)(b << 10) + r) << 6) + c] = o;
  }
}

// ---------------------------------------------------------------------------
extern "C" void kernel_launch(void* const* d_in, const int* in_sizes, int n_in,
                              void* d_out, int out_size, void* d_ws, size_t ws_size,
                              hipStream_t stream) {
  const float* x         = (const float*)d_in[0];
  const float* kb        = (const float*)d_in[1];
  const float* kernel_W  = (const float*)d_in[2];
  const float* conv_bias = (const float*)d_in[3];
  const float* ln_scale  = (const float*)d_in[4];
  const float* ln_bias   = (const float*)d_in[5];
  const float* W1        = (const float*)d_in[6];
  const float* b1        = (const float*)d_in[7];
  const float* W2        = (const float*)d_in[8];
  const float* b2        = (const float*)d_in[9];
  float* out = (float*)d_out;

  // Workspace: ghi 8.4MB | glo 8.4MB | part 128*2*256KB = 67MB (ws ~1GB)
  char* wsb = (char*)d_ws;
  u16* ghi = (u16*)wsb;
  u16* glo = (u16*)(wsb + 8388608);
  float* part = (float*)(wsb + 16777216);
  const int Sk = 128;   // one 256-k window per (ks,b)

  build_g<<<2048, 256, 0, stream>>>(x, kernel_W, ghi, glo);
  gemm_nolds<<<dim3(2, Sk, 2), 256, 0, stream>>>(kb, ghi, glo, part);
  epilogue<<<dim3(2048), 256, 0, stream>>>(part, conv_bias, ln_scale, ln_bias,
                                           W1, b1, W2, b2, out, Sk);
}

// Round 15
// 102.184 us; speedup vs baseline: 3.9073x; 1.8456x over previous
//
#include <hip/hip_runtime.h>
#include <stdint.h>

typedef float  f32x4 __attribute__((ext_vector_type(4)));
typedef short  s16x8 __attribute__((ext_vector_type(8)));
typedef unsigned short u16;

#define KK 32768   /* NN*DD */

__device__ __forceinline__ u16 f2bf_rn(float f) {
  uint32_t u = __float_as_uint(f);
  u += 0x7fffu + ((u >> 16) & 1u);
  return (u16)(u >> 16);
}
__device__ __forceinline__ float bf2f(u16 h) {
  return __uint_as_float(((uint32_t)h) << 16);
}

// global -> LDS direct DMA, 16B per lane. LDS dest = wave-uniform base + lane*16.
__device__ __forceinline__ void gload_lds16(const void* g, void* l) {
  __builtin_amdgcn_global_load_lds(
      (const __attribute__((address_space(1))) uint32_t*)g,
      (__attribute__((address_space(3))) uint32_t*)l, 16, 0, 0);
}

// ---------------------------------------------------------------------------
// Kernel A: g_t[b][c][k] = x[b,s,c] * W[d,c], k = s*32+d, LINEAR layout,
// bf16 hi/lo planes. (GEMM holds B fragments in registers.)
// ---------------------------------------------------------------------------
__global__ void build_g(const float* __restrict__ x, const float* __restrict__ W,
                        u16* __restrict__ ghi, u16* __restrict__ glo) {
  int t  = blockIdx.x * 256 + threadIdx.x;
  int k0 = (t & 4095) << 3;
  int c  = (t >> 12) & 63;
  int b  = t >> 18;
  int s  = k0 >> 5;
  int d0 = k0 & 31;
  float xv = x[(((b << 10) + s) << 6) + c];
  s16x8 vh, vl;
#pragma unroll
  for (int i = 0; i < 8; ++i) {
    float g = xv * W[((d0 + i) << 6) + c];
    u16 h = f2bf_rn(g);
    vh[i] = (short)h;
    vl[i] = (short)f2bf_rn(g - bf2f(h));
  }
  size_t off = (((size_t)((b << 6) + c)) << 15) + (size_t)k0;
  *reinterpret_cast<s16x8*>(ghi + off) = vh;
  *reinterpret_cast<s16x8*>(glo + off) = vl;
}

// ---------------------------------------------------------------------------
// Kernel B: A-only-staged GEMM. Grid (1,128,2) = 256 WGs (1/CU), 512 thr =
// 8 waves (2 rf x 4 cf); wave owns 16 rows x 16 cols per 32-row m-subtile.
// B: BH[8]+BL[8] = 64 VGPRs/lane (k-window 256), loaded ONCE (VGPR ~120,
//   no spill — r14's failure mode eliminated by sizing).
// A: fp32 via global_load_lds, one instr = 1KB CONTIGUOUS from one kb row
//   (ideal DRAM), source pre-swizzled ^((row&7)<<4) (16B units), LDS linear;
//   read back XOR-swizzled (slot-uniform -> conflict-free floor), hi/lo
//   convert in-reg. Triple-buffered 3x32KB; stage AFTER barrier (WAR-safe);
//   per-wave counted vmcnt (4 gloads + 4 dword stores per iter).
// ---------------------------------------------------------------------------
#define MFMA16(A_, B_, C_) __builtin_amdgcn_mfma_f32_16x16x32_bf16((A_), (B_), (C_), 0, 0, 0)

__global__ __launch_bounds__(512) void gemm_breg(
    const float* __restrict__ kb, const u16* __restrict__ ghi,
    const u16* __restrict__ glo, float* __restrict__ part) {
  __shared__ unsigned char lds[98304];

  const int tid = threadIdx.x;
  const int w   = tid >> 6;      // wave 0..7
  const int l   = tid & 63;
  const int lr  = l & 15;
  const int lk  = l >> 4;
  const int ks  = blockIdx.y;    // k-window [ks*256, +256)
  const int b   = blockIdx.z;
  const int rf  = w >> 2;        // row-half 0..1
  const int cf  = w & 3;         // col-quarter 0..3

  // ---- B fragments -> 64 VGPRs, once (col = cf*16+lr, k = kf*32 + lk*8) ----
  s16x8 BH[8], BL[8];
#pragma unroll
  for (int kf = 0; kf < 8; ++kf) {
    size_t off = (((size_t)((b << 6) + (cf << 4) + lr)) << 15)
               + (size_t)((ks << 8) + (kf << 5) + (lk << 3));
    BH[kf] = *reinterpret_cast<const s16x8*>(ghi + off);
    BL[kf] = *reinterpret_cast<const s16x8*>(glo + off);
  }

  // ---- A staging: wave w stages rows 4w..4w+3; instr i = row 4w+i,
  //      1KB contiguous (lane*16), source col pre-swizzled ^((row&7)<<4) ----
  const float* asrc[4];
#pragma unroll
  for (int i = 0; i < 4; ++i) {
    int row = 4 * w + i;                       // 0..31 within subtile
    int cs  = (l << 4) ^ ((row & 7) << 4);     // byte offset within 1KB row
    asrc[i] = kb + (((size_t)((b << 10) + row)) << 15)
                 + (size_t)(ks << 8) + (size_t)(cs >> 2);
  }
  const int ldst = (w << 12);                  // wave LDS base (4KB/wave)

  // ---- A read addressing (frag layout: row=lane&15 (+rf*16), k=lk*8+e) ----
  const int r     = (rf << 4) + lr;            // 0..31
  const int rbase = r << 10;                   // r*1024
  const int rswz  = (r & 7) << 4;

  float* const pbase = part + (((size_t)((b << 7) + ks)) << 16);

#define STAGE(MT_) do {                                                       \
    size_t moff_ = (size_t)(MT_) << 20;  /* mt*32 rows * 32768 elems */       \
    _Pragma("unroll")                                                         \
    for (int i = 0; i < 4; ++i)                                               \
      gload_lds16(asrc[i] + moff_, lds + ((MT_) % 3) * 32768 + ldst + (i << 10)); \
  } while (0)

  // prologue
  STAGE(0);
  STAGE(1);

  for (int mt = 0; mt < 32; ++mt) {
    // wait own gloads of tile mt (per-wave exact in-order counts)
    if (mt == 0)       asm volatile("s_waitcnt vmcnt(4)" ::: "memory");
    else if (mt == 1)  asm volatile("s_waitcnt vmcnt(8)" ::: "memory");
    else if (mt == 31) asm volatile("s_waitcnt vmcnt(8)" ::: "memory");
    else               asm volatile("s_waitcnt vmcnt(12)" ::: "memory");
    __builtin_amdgcn_sched_barrier(0);
    __builtin_amdgcn_s_barrier();            // all waves' tile-mt staged;
                                             // all done computing mt-1
    if (mt + 2 < 32) STAGE(mt + 2);          // overwrites buf (mt-1)%3: safe

    const unsigned char* LA = lds + (mt % 3) * 32768;
    f32x4 acc = {0.f, 0.f, 0.f, 0.f};
#pragma unroll
    for (int kf = 0; kf < 8; ++kf) {
      int cb = (kf << 7) + (lk << 5);
      f32x4 a0 = *reinterpret_cast<const f32x4*>(LA + rbase + ( cb       ^ rswz));
      f32x4 a1 = *reinterpret_cast<const f32x4*>(LA + rbase + ((cb + 16) ^ rswz));
      s16x8 ah, al;
#pragma unroll
      for (int e = 0; e < 8; ++e) {
        float f = (e < 4) ? a0[e] : a1[e - 4];
        uint32_t u = __float_as_uint(f);
        ((short*)&ah)[e] = (short)(u16)(u >> 16);
        ((short*)&al)[e] = (short)f2bf_rn(f - __uint_as_float(u & 0xffff0000u));
      }
      acc = MFMA16(ah, BH[kf], acc);
      acc = MFMA16(al, BH[kf], acc);
      acc = MFMA16(ah, BL[kf], acc);
    }

    // 4 dword stores: rr = mt*32 + rf*16 + lk*4 + i, cc = cf*16 + lr
    float* pp = pbase + (((size_t)((mt << 5) + (rf << 4) + (lk << 2))) << 6)
                      + (cf << 4) + lr;
#pragma unroll
    for (int i = 0; i < 4; ++i) pp[(size_t)i << 6] = acc[i];
  }
#undef STAGE
}

// ---------------------------------------------------------------------------
// Kernel C: per (b,r): reduce Sk partials + conv_bias -> LayerNorm -> MLP.
// ---------------------------------------------------------------------------
__device__ __forceinline__ float gelu_tanh(float v) {
  float u = 0.7978845608028654f * (v + 0.044715f * v * v * v);
  float e = __expf(2.0f * u);
  float th = 1.0f - 2.0f / (e + 1.0f);
  return 0.5f * v * (1.0f + th);
}

__global__ __launch_bounds__(256) void epilogue(
    const float* __restrict__ part, const float* __restrict__ conv_bias,
    const float* __restrict__ ln_scale, const float* __restrict__ ln_bias,
    const float* __restrict__ W1, const float* __restrict__ b1,
    const float* __restrict__ W2, const float* __restrict__ b2,
    float* __restrict__ out, int Sk) {
  __shared__ float red[4][64];
  __shared__ float nbuf[64];
  __shared__ float hbuf[256];

  const int tid = threadIdx.x;
  const int b = blockIdx.x >> 10;
  const int r = blockIdx.x & 1023;
  const int c = tid & 63;
  const int q = tid >> 6;

  float s = 0.0f;
  for (int ks = q; ks < Sk; ks += 4)
    s += part[(((size_t)(b * Sk + ks)) << 16) + ((size_t)r << 6) + c];
  red[q][c] = s;
  __syncthreads();

  if (q == 0) {
    float a = red[0][c] + red[1][c] + red[2][c] + red[3][c] + conv_bias[c];
    float sum = a;
#pragma unroll
    for (int off = 32; off >= 1; off >>= 1) sum += __shfl_xor(sum, off);
    float mu = sum * (1.0f / 64.0f);
    float d = a - mu;
    float ss = d * d;
#pragma unroll
    for (int off = 32; off >= 1; off >>= 1) ss += __shfl_xor(ss, off);
    float var = ss * (1.0f / 64.0f);
    nbuf[c] = d * rsqrtf(var + 1e-6f) * ln_scale[c] + ln_bias[c];
  }
  __syncthreads();

  {
    float acc = b1[tid];
#pragma unroll 8
    for (int cc = 0; cc < 64; ++cc) acc += nbuf[cc] * W1[(cc << 8) + tid];
    hbuf[tid] = gelu_tanh(acc);
  }
  __syncthreads();

  {
    float po = 0.0f;
#pragma unroll 8
    for (int jj = 0; jj < 64; ++jj) {
      int j = (q << 6) + jj;
      po += hbuf[j] * W2[(j << 6) + c];
    }
    red[q][c] = po;
  }
  __syncthreads();
  if (tid < 64) {
    float o = red[0][c] + red[1][c] + red[2][c] + red[3][c] + b2[c];
    out[(((size_t)(b << 10) + r) << 6) + c] = o;
  }
}

// ---------------------------------------------------------------------------
extern "C" void kernel_launch(void* const* d_in, const int* in_sizes, int n_in,
                              void* d_out, int out_size, void* d_ws, size_t ws_size,
                              hipStream_t stream) {
  const float* x         = (const float*)d_in[0];
  const float* kb        = (const float*)d_in[1];
  const float* kernel_W  = (const float*)d_in[2];
  const float* conv_bias = (const float*)d_in[3];
  const float* ln_scale  = (const float*)d_in[4];
  const float* ln_bias   = (const float*)d_in[5];
  const float* W1        = (const float*)d_in[6];
  const float* b1        = (const float*)d_in[7];
  const float* W2        = (const float*)d_in[8];
  const float* b2        = (const float*)d_in[9];
  float* out = (float*)d_out;

  // Workspace: ghi 8.4MB | glo 8.4MB | part 128*2*256KB = 67MB (ws ~1GB)
  char* wsb = (char*)d_ws;
  u16* ghi = (u16*)wsb;
  u16* glo = (u16*)(wsb + 8388608);
  float* part = (float*)(wsb + 16777216);
  const int Sk = 128;   // one 256-k window per (ks,b)

  build_g<<<2048, 256, 0, stream>>>(x, kernel_W, ghi, glo);
  gemm_breg<<<dim3(1, Sk, 2), 512, 0, stream>>>(kb, ghi, glo, part);
  epilogue<<<dim3(2048), 256, 0, stream>>>(part, conv_bias, ln_scale, ln_bias,
                                           W1, b1, W2, b2, out, Sk);
}